// Round 1
// baseline (329.613 us; speedup 1.0000x reference)
//
#include <hip/hip_runtime.h>

// Problem constants: pred/target (4,4,64,128,128) fp32 -> N=B*C=16 volumes of 64x128x128.
#define NB 16
#define DD 64
#define HH 128
#define WW 128

constexpr int TD = 4, TH = 8, TW = 32;          // output tile per block
constexpr int LZ = TD + 2, LY = TH + 2, LX = TW + 2;  // 6 x 10 x 34 halo tile
constexpr int TILE_ELEMS = LZ * LY * LX;        // 2040
constexpr float INV_COUNT = 1.0f / (3.0f * 16.0f * 64.0f * 128.0f * 128.0f); // 1/50331648

__global__ void zero_out_kernel(float* out) {
    if (threadIdx.x == 0 && blockIdx.x == 0) out[0] = 0.0f;
}

__global__ __launch_bounds__(256) void sobel_l1_kernel(
    const float* __restrict__ pred,
    const float* __restrict__ target,
    float* __restrict__ out)
{
    __shared__ float t[LZ][LY][LX];
    __shared__ float wsum[4];

    const int tid = threadIdx.x;
    int b = blockIdx.x;
    const int bw = b & 3;  b >>= 2;   // 128/32 = 4 w-tiles
    const int bh = b & 15; b >>= 4;   // 128/8 = 16 h-tiles
    const int bd = b & 15; b >>= 4;   // 64/4 = 16 d-tiles
    const int bn = b;                 // 16 volumes

    const int w0 = bw * TW, h0 = bh * TH, d0 = bd * TD;
    const size_t nbase = (size_t)bn * (DD * HH * WW);

    // ---- load diff tile (with halo, zero-padded at volume borders) ----
    for (int i = tid; i < TILE_ELEMS; i += 256) {
        const int dx = i % LX;
        const int r  = i / LX;
        const int dy = r % LY;
        const int dz = r / LY;
        const int gw = w0 - 1 + dx;
        const int gh = h0 - 1 + dy;
        const int gd = d0 - 1 + dz;
        float v = 0.0f;
        if ((unsigned)gw < WW && (unsigned)gh < HH && (unsigned)gd < DD) {
            const size_t idx = nbase + (size_t)gd * (HH * WW) + (size_t)gh * WW + gw;
            v = pred[idx] - target[idx];
        }
        t[dz][dy][dx] = v;
    }
    __syncthreads();

    // ---- compute: each thread owns one (h,w) column, slides along d ----
    const int lw = tid & 31;   // 0..31
    const int lh = tid >> 5;   // 0..7

    // Per-plane partial reductions:
    //   A  = sum s(j)s(k) v   (smooth-smooth)
    //   Bh = sum d(j)s(k) v   (d along H)
    //   Bw = sum s(j)d(k) v   (d along W)
    auto plane = [&](int z, float& A_, float& Bh_, float& Bw_) {
        const float p00 = t[z][lh + 0][lw + 0];
        const float p01 = t[z][lh + 0][lw + 1];
        const float p02 = t[z][lh + 0][lw + 2];
        const float p10 = t[z][lh + 1][lw + 0];
        const float p11 = t[z][lh + 1][lw + 1];
        const float p12 = t[z][lh + 1][lw + 2];
        const float p20 = t[z][lh + 2][lw + 0];
        const float p21 = t[z][lh + 2][lw + 1];
        const float p22 = t[z][lh + 2][lw + 2];
        const float r0s = p00 + 2.0f * p01 + p02;
        const float r1s = p10 + 2.0f * p11 + p12;
        const float r2s = p20 + 2.0f * p21 + p22;
        const float r0d = p02 - p00;
        const float r1d = p12 - p10;
        const float r2d = p22 - p20;
        A_  = r0s + 2.0f * r1s + r2s;
        Bh_ = r2s - r0s;
        Bw_ = r0d + 2.0f * r1d + r2d;
    };

    float A[3], Bh[3], Bw[3];
    float acc = 0.0f;

    plane(0, A[0], Bh[0], Bw[0]);
    plane(1, A[1], Bh[1], Bw[1]);

#pragma unroll
    for (int ld = 0; ld < TD; ++ld) {
        const int s0 = ld % 3;
        const int s1 = (ld + 1) % 3;
        const int s2 = (ld + 2) % 3;
        plane(ld + 2, A[s2], Bh[s2], Bw[s2]);
        const float rd = A[s2] - A[s0];                       // d along D
        const float rh = Bh[s0] + 2.0f * Bh[s1] + Bh[s2];     // d along H
        const float rw = Bw[s0] + 2.0f * Bw[s1] + Bw[s2];     // d along W
        acc += fabsf(rd) + fabsf(rh) + fabsf(rw);
    }

    // ---- block reduction ----
#pragma unroll
    for (int off = 32; off > 0; off >>= 1)
        acc += __shfl_down(acc, off, 64);
    const int wave = tid >> 6;
    if ((tid & 63) == 0) wsum[wave] = acc;
    __syncthreads();
    if (tid == 0) {
        const float s = wsum[0] + wsum[1] + wsum[2] + wsum[3];
        atomicAdd(out, s * INV_COUNT);
    }
}

extern "C" void kernel_launch(void* const* d_in, const int* in_sizes, int n_in,
                              void* d_out, int out_size, void* d_ws, size_t ws_size,
                              hipStream_t stream) {
    const float* pred   = (const float*)d_in[0];
    const float* target = (const float*)d_in[1];
    float* out = (float*)d_out;

    zero_out_kernel<<<1, 64, 0, stream>>>(out);

    // grid: 16 n * 16 dTiles * 16 hTiles * 4 wTiles = 16384 blocks
    const int nblocks = NB * (DD / TD) * (HH / TH) * (WW / TW);
    sobel_l1_kernel<<<nblocks, 256, 0, stream>>>(pred, target, out);
}

// Round 2
// 184.578 us; speedup vs baseline: 1.7858x; 1.7858x over previous
//
#include <hip/hip_runtime.h>

// pred/target (4,4,64,128,128) fp32 -> 16 volumes of 64x128x128.
#define NB 16
#define DD 64
#define HH 128
#define WW 128

constexpr int TD = 4, TH = 8;                 // output tile: 4 x 8 x 128(full W)
constexpr int LZ = TD + 2, LY = TH + 2;       // 6 x 10 halo planes/rows
constexpr int LXF = 136;                      // 4 left pad + 128 + 4 right pad (floats)
constexpr int NROWS = LZ * LY;                // 60
constexpr float INV_COUNT = 1.0f / 50331648.0f; // 1/(3*16*64*128*128)

__global__ void zero_out_kernel(float* out) {
    if (threadIdx.x == 0 && blockIdx.x == 0) out[0] = 0.0f;
}

__global__ __launch_bounds__(256) void sobel_l1_kernel(
    const float* __restrict__ pred,
    const float* __restrict__ target,
    float* __restrict__ out)
{
    __shared__ float t[NROWS * LXF];          // ~32.6 KB
    __shared__ float wsum[4];

    const int tid = threadIdx.x;
    int b = blockIdx.x;
    const int bh = b & 15; b >>= 4;           // 128/8  = 16 h-tiles
    const int bd = b & 15; b >>= 4;           // 64/4   = 16 d-tiles
    const int bn = b;                         // 16 volumes

    const int h0 = bh * TH, d0 = bd * TD;
    const size_t nbase = (size_t)bn * (DD * HH * WW);

    // ---- zero the W-halo pads (only float idx 3 and 132 are read; pad all) ----
    for (int i = tid; i < NROWS * 2; i += 256) {
        const int row = i >> 1;
        const int side = i & 1;
        *(float4*)&t[row * LXF + side * 132] = float4{0.f, 0.f, 0.f, 0.f};
    }

    // ---- coalesced float4 diff load: 60 rows x 32 quads ----
    for (int i = tid; i < NROWS * 32; i += 256) {
        const int wq  = i & 31;               // w quad 0..31
        const int row = i >> 5;               // 0..59
        const int y   = row % LY;             // 0..9
        const int z   = row / LY;             // 0..5
        const int gh  = h0 - 1 + y;
        const int gd  = d0 - 1 + z;
        float4 v = float4{0.f, 0.f, 0.f, 0.f};
        if ((unsigned)gh < HH && (unsigned)gd < DD) {
            const size_t idx = nbase + ((size_t)gd * HH + gh) * WW + 4 * wq;
            const float4 p = *(const float4*)(pred + idx);
            const float4 q = *(const float4*)(target + idx);
            v = float4{p.x - q.x, p.y - q.y, p.z - q.z, p.w - q.w};
        }
        *(float4*)&t[row * LXF + 4 + 4 * wq] = v;
    }
    __syncthreads();

    // ---- compute: thread owns 4 contiguous w outputs, one h row, slides over z ----
    const int tc = tid & 31;                  // w-quad
    const int lh = tid >> 5;                  // 0..7

    // Per-plane partials (float4 over 4 w's):
    //   A  = s(h) s(w) v,  Bh = d(h) s(w) v,  Bw = s(h) d(w) v
    auto plane = [&](int z, float4& A_, float4& Bh_, float4& Bw_) {
        float4 rs[3], rdv[3];
#pragma unroll
        for (int r = 0; r < 3; ++r) {
            const float* row = &t[(z * LY + lh + r) * LXF];
            const float4 bq = *(const float4*)(row + 4 * tc + 4);  // centers w..w+3
            const float  lm = row[4 * tc + 3];                     // w-1
            const float  rp = row[4 * tc + 8];                     // w+4
            // vm1 = {lm, bq.x, bq.y, bq.z}; vp1 = {bq.y, bq.z, bq.w, rp}
            rs[r]  = float4{lm   + 2.f * bq.x + bq.y,
                            bq.x + 2.f * bq.y + bq.z,
                            bq.y + 2.f * bq.z + bq.w,
                            bq.z + 2.f * bq.w + rp};
            rdv[r] = float4{bq.y - lm, bq.z - bq.x, bq.w - bq.y, rp - bq.z};
        }
        A_  = float4{rs[0].x + 2.f * rs[1].x + rs[2].x,
                     rs[0].y + 2.f * rs[1].y + rs[2].y,
                     rs[0].z + 2.f * rs[1].z + rs[2].z,
                     rs[0].w + 2.f * rs[1].w + rs[2].w};
        Bh_ = float4{rs[2].x - rs[0].x, rs[2].y - rs[0].y,
                     rs[2].z - rs[0].z, rs[2].w - rs[0].w};
        Bw_ = float4{rdv[0].x + 2.f * rdv[1].x + rdv[2].x,
                     rdv[0].y + 2.f * rdv[1].y + rdv[2].y,
                     rdv[0].z + 2.f * rdv[1].z + rdv[2].z,
                     rdv[0].w + 2.f * rdv[1].w + rdv[2].w};
    };

    float4 A[3], Bh[3], Bw[3];
    float acc = 0.0f;

    plane(0, A[0], Bh[0], Bw[0]);
    plane(1, A[1], Bh[1], Bw[1]);

#pragma unroll
    for (int ld = 0; ld < TD; ++ld) {
        const int s0 = ld % 3;
        const int s1 = (ld + 1) % 3;
        const int s2 = (ld + 2) % 3;
        plane(ld + 2, A[s2], Bh[s2], Bw[s2]);
        const float4 a0 = A[s0], a2 = A[s2];
        const float4 b0 = Bh[s0], b1 = Bh[s1], b2 = Bh[s2];
        const float4 c0 = Bw[s0], c1 = Bw[s1], c2 = Bw[s2];
        acc += fabsf(a2.x - a0.x) + fabsf(a2.y - a0.y)
             + fabsf(a2.z - a0.z) + fabsf(a2.w - a0.w);
        acc += fabsf(b0.x + 2.f * b1.x + b2.x) + fabsf(b0.y + 2.f * b1.y + b2.y)
             + fabsf(b0.z + 2.f * b1.z + b2.z) + fabsf(b0.w + 2.f * b1.w + b2.w);
        acc += fabsf(c0.x + 2.f * c1.x + c2.x) + fabsf(c0.y + 2.f * c1.y + c2.y)
             + fabsf(c0.z + 2.f * c1.z + c2.z) + fabsf(c0.w + 2.f * c1.w + c2.w);
    }

    // ---- block reduction ----
#pragma unroll
    for (int off = 32; off > 0; off >>= 1)
        acc += __shfl_down(acc, off, 64);
    const int wave = tid >> 6;
    if ((tid & 63) == 0) wsum[wave] = acc;
    __syncthreads();
    if (tid == 0) {
        const float s = wsum[0] + wsum[1] + wsum[2] + wsum[3];
        atomicAdd(out, s * INV_COUNT);
    }
}

extern "C" void kernel_launch(void* const* d_in, const int* in_sizes, int n_in,
                              void* d_out, int out_size, void* d_ws, size_t ws_size,
                              hipStream_t stream) {
    const float* pred   = (const float*)d_in[0];
    const float* target = (const float*)d_in[1];
    float* out = (float*)d_out;

    zero_out_kernel<<<1, 64, 0, stream>>>(out);

    // 16 volumes * 16 d-tiles * 16 h-tiles = 4096 blocks
    const int nblocks = NB * (DD / TD) * (HH / TH);
    sobel_l1_kernel<<<nblocks, 256, 0, stream>>>(pred, target, out);
}

// Round 3
// 173.388 us; speedup vs baseline: 1.9010x; 1.0645x over previous
//
#include <hip/hip_runtime.h>

// pred/target (4,4,64,128,128) fp32 -> 16 volumes of 64x128x128.
#define NB 16
#define DD 64
#define HH 128
#define WW 128

constexpr int TH = 8;            // output rows per block
constexpr int CD = 8;            // output planes per block (D-chunk)
constexpr int LY = TH + 2;       // 10 rows incl. halo
constexpr float INV_COUNT = 1.0f / 50331648.0f; // 1/(3*16*64*128*128)

__global__ void zero_out_kernel(float* out) {
    if (threadIdx.x == 0 && blockIdx.x == 0) out[0] = 0.0f;
}

__global__ __launch_bounds__(256) void sobel_l1_kernel(
    const float* __restrict__ pred,
    const float* __restrict__ target,
    float* __restrict__ out)
{
    __shared__ float buf[2][LY * WW];   // 2 x 10 x 128 floats = 10 KB
    __shared__ float wsum[4];

    const int tid = threadIdx.x;
    int b = blockIdx.x;
    const int bh = b & 15; b >>= 4;     // 16 h-tiles
    const int bc = b & 7;  b >>= 3;     // 8 d-chunks
    const int bn = b;                   // 16 volumes

    const int h0 = bh * TH;
    const int d0 = bc * CD;
    const size_t nbase = (size_t)bn * (DD * HH * WW);

    const int tc  = tid & 31;           // w-quad / lane-in-row
    const int lh  = tid >> 5;           // 0..7 (also load row for v0)

    // ---- plane load: 10 rows x 32 quads = 320 float4; thread does row lh (v0)
    //      and, for tid<64, row 8+(tid>>5) (v1). Zero outside volume. ----
    auto load_plane = [&](int gd, float4& v0, float4& v1) {
        v0 = float4{0.f, 0.f, 0.f, 0.f};
        v1 = float4{0.f, 0.f, 0.f, 0.f};
        if ((unsigned)gd < DD) {
            const size_t pbase = nbase + (size_t)gd * (HH * WW);
            const int gh = h0 - 1 + lh;
            if ((unsigned)gh < HH) {
                const size_t idx = pbase + (size_t)gh * WW + 4 * tc;
                const float4 p = *(const float4*)(pred + idx);
                const float4 q = *(const float4*)(target + idx);
                v0 = float4{p.x - q.x, p.y - q.y, p.z - q.z, p.w - q.w};
            }
            if (tid < 64) {
                const int gh2 = h0 - 1 + 8 + lh;   // rows 8,9
                if ((unsigned)gh2 < HH) {
                    const size_t idx = pbase + (size_t)gh2 * WW + 4 * tc;
                    const float4 p = *(const float4*)(pred + idx);
                    const float4 q = *(const float4*)(target + idx);
                    v1 = float4{p.x - q.x, p.y - q.y, p.z - q.z, p.w - q.w};
                }
            }
        }
    };

    auto store_plane = [&](int p, const float4& v0, const float4& v1) {
        float* B = buf[p];
        *(float4*)&B[lh * WW + 4 * tc] = v0;
        if (tid < 64)
            *(float4*)&B[(8 + lh) * WW + 4 * tc] = v1;
    };

    // ---- per-plane partials for this thread's 4 outputs:
    //      A = s(h)s(w)v, Bh = d(h)s(w)v, Bw = s(h)d(w)v ----
    auto partial = [&](int p, float4& A_, float4& Bh_, float4& Bw_) {
        const float* B = buf[p];
        float4 rs[3], rdw[3];
#pragma unroll
        for (int r = 0; r < 3; ++r) {
            const float4 q = *(const float4*)&B[(lh + r) * WW + 4 * tc];
            float lm = __shfl_up(q.w, 1, 32);
            float rp = __shfl_down(q.x, 1, 32);
            if (tc == 0)  lm = 0.f;   // w = -1: volume border
            if (tc == 31) rp = 0.f;   // w = 128: volume border
            rs[r]  = float4{lm  + 2.f * q.x + q.y,
                            q.x + 2.f * q.y + q.z,
                            q.y + 2.f * q.z + q.w,
                            q.z + 2.f * q.w + rp};
            rdw[r] = float4{q.y - lm, q.z - q.x, q.w - q.y, rp - q.z};
        }
        A_  = float4{rs[0].x + 2.f * rs[1].x + rs[2].x,
                     rs[0].y + 2.f * rs[1].y + rs[2].y,
                     rs[0].z + 2.f * rs[1].z + rs[2].z,
                     rs[0].w + 2.f * rs[1].w + rs[2].w};
        Bh_ = float4{rs[2].x - rs[0].x, rs[2].y - rs[0].y,
                     rs[2].z - rs[0].z, rs[2].w - rs[0].w};
        Bw_ = float4{rdw[0].x + 2.f * rdw[1].x + rdw[2].x,
                     rdw[0].y + 2.f * rdw[1].y + rdw[2].y,
                     rdw[0].z + 2.f * rdw[1].z + rdw[2].z,
                     rdw[0].w + 2.f * rdw[1].w + rdw[2].w};
    };

    // ---- prologue: planes d0-1 (buf0), d0 (buf1) ----
    float4 rA[3], rBh[3], rBw[3];
    {
        float4 a0, a1, b0v, b1v;
        load_plane(d0 - 1, a0, a1);
        load_plane(d0,     b0v, b1v);
        store_plane(0, a0, a1);
        store_plane(1, b0v, b1v);
        __syncthreads();
        partial(0, rA[0], rBh[0], rBw[0]);
        partial(1, rA[1], rBh[1], rBw[1]);
    }

    float acc = 0.0f;
#pragma unroll
    for (int ld = 0; ld < CD; ++ld) {
        // plane z = d0+ld+1 goes into buf[ld&1] (overwrites plane d0+ld-1)
        float4 c0, c1;
        load_plane(d0 + ld + 1, c0, c1);
        __syncthreads();                 // everyone done reading buf[ld&1]
        store_plane(ld & 1, c0, c1);
        __syncthreads();                 // writes visible
        const int s0 = ld % 3, s1 = (ld + 1) % 3, s2 = (ld + 2) % 3;
        partial(ld & 1, rA[s2], rBh[s2], rBw[s2]);

        const float4 a0 = rA[s0],  a2 = rA[s2];
        const float4 b0 = rBh[s0], b1 = rBh[s1], b2 = rBh[s2];
        const float4 c0v = rBw[s0], c1v = rBw[s1], c2v = rBw[s2];
        acc += fabsf(a2.x - a0.x) + fabsf(a2.y - a0.y)
             + fabsf(a2.z - a0.z) + fabsf(a2.w - a0.w);
        acc += fabsf(b0.x + 2.f * b1.x + b2.x) + fabsf(b0.y + 2.f * b1.y + b2.y)
             + fabsf(b0.z + 2.f * b1.z + b2.z) + fabsf(b0.w + 2.f * b1.w + b2.w);
        acc += fabsf(c0v.x + 2.f * c1v.x + c2v.x) + fabsf(c0v.y + 2.f * c1v.y + c2v.y)
             + fabsf(c0v.z + 2.f * c1v.z + c2v.z) + fabsf(c0v.w + 2.f * c1v.w + c2v.w);
    }

    // ---- block reduction ----
#pragma unroll
    for (int off = 32; off > 0; off >>= 1)
        acc += __shfl_down(acc, off, 64);
    const int wave = tid >> 6;
    if ((tid & 63) == 0) wsum[wave] = acc;
    __syncthreads();
    if (tid == 0) {
        const float s = wsum[0] + wsum[1] + wsum[2] + wsum[3];
        atomicAdd(out, s * INV_COUNT);
    }
}

extern "C" void kernel_launch(void* const* d_in, const int* in_sizes, int n_in,
                              void* d_out, int out_size, void* d_ws, size_t ws_size,
                              hipStream_t stream) {
    const float* pred   = (const float*)d_in[0];
    const float* target = (const float*)d_in[1];
    float* out = (float*)d_out;

    zero_out_kernel<<<1, 64, 0, stream>>>(out);

    // 16 volumes * 8 d-chunks * 16 h-tiles = 2048 blocks
    const int nblocks = NB * (DD / CD) * (HH / TH);
    sobel_l1_kernel<<<nblocks, 256, 0, stream>>>(pred, target, out);
}